// Round 4
// baseline (5673.669 us; speedup 1.0000x reference)
//
#include <hip/hip_runtime.h>
#include <stdint.h>

#define TN_D 1024
#define TN_F 1024
#define SENT32 0xAAAAAAAAu
#define NBLK 64
#define UPB 16            // u-indices owned per block (1 per wave)
#define NR (TN_F / 2)     // fused rounds: 2 chain steps per round

typedef _Float16 half4_t __attribute__((ext_vector_type(4)));
typedef unsigned long long u64;

// ---------------------------------------------------------------------------
// Transpose + convert: core[s][i][j] f32 -> coreT[s][j][i] f16.
// ---------------------------------------------------------------------------
__global__ __launch_bounds__(256) void tn_transpose(const float* __restrict__ core,
                                                    _Float16* __restrict__ coreT) {
    __shared__ float tile[64][65];
    const int s = blockIdx.z;
    const size_t base = (size_t)s * TN_D * TN_D;
    const int j0 = blockIdx.x * 64;
    const int i0 = blockIdx.y * 64;
    const int tx = threadIdx.x;
    const int ty = threadIdx.y;
#pragma unroll
    for (int r = 0; r < 4; ++r) {
        const int ii = ty + 16 * r;
        const float4 v = *(const float4*)&core[base + (size_t)(i0 + ii) * TN_D + j0 + 4 * tx];
        tile[ii][4 * tx + 0] = v.x; tile[ii][4 * tx + 1] = v.y;
        tile[ii][4 * tx + 2] = v.z; tile[ii][4 * tx + 3] = v.w;
    }
    __syncthreads();
#pragma unroll
    for (int r = 0; r < 4; ++r) {
        const int jj = ty + 16 * r;
        _Float16 h4[4];
        h4[0] = (_Float16)tile[4 * tx + 0][jj];
        h4[1] = (_Float16)tile[4 * tx + 1][jj];
        h4[2] = (_Float16)tile[4 * tx + 2][jj];
        h4[3] = (_Float16)tile[4 * tx + 3][jj];
        *(uint64_t*)&coreT[base + (size_t)(j0 + jj) * TN_D + i0 + 4 * tx] = *(uint64_t*)h4;
    }
}

__device__ __forceinline__ float dot4h(float4 a, half4_t h) {
    return a.x * (float)h[0] + a.y * (float)h[1] + a.z * (float)h[2] + a.w * (float)h[3];
}

__device__ __forceinline__ u64 aload(const u64* p) {
    return __hip_atomic_load(p, __ATOMIC_RELAXED, __HIP_MEMORY_SCOPE_AGENT);
}

// ---------------------------------------------------------------------------
// Fused 2-step chain, contention-free. acc layout: [2 slots][NBLK][TN_D] u64,
// each u64 = (tag << 32) | f32 bits. Partials of round r carry tag r+1 in
// slot r&1; consumed at round r+1. Depth-2 reuse is safe: a block stores
// round-r partials only after its round-r poll saw ALL tag-r... (i.e. every
// block finished writing round r-1, hence finished READING slot (r-2)&1).
// No contended RMW, no counters, no fences: ordering via data dependence
// (store value depends on completed poll loads) + monotone tags.
// ---------------------------------------------------------------------------
__global__ __launch_bounds__(1024, 1) void tn_chain_fused(const int* __restrict__ x,
                                                          const _Float16* __restrict__ matT,
                                                          const float* __restrict__ mat32,
                                                          const float* __restrict__ left,
                                                          const float* __restrict__ right,
                                                          u64* __restrict__ acc,
                                                          float* __restrict__ out) {
    __shared__ __align__(16) float lv[TN_D];  // broadcast v_{2r}
    __shared__ __align__(16) float wl[UPB];   // this block's u slice
    __shared__ int xs[TN_F];

    const int tid = threadIdx.x;
    const int w = tid >> 6;
    const int l = tid & 63;
    const int b = blockIdx.x;
    const int iw = UPB * b + w;  // phase-A column owned by this wave

    xs[tid] = x[tid];
    __syncthreads();

    half4_t A0, A1, A2, A3, nA0, nA1, nA2, nA3;
    {
        const half4_t* cp = (const half4_t*)(matT + ((size_t)xs[0] * TN_D + iw) * TN_D);
        A0 = cp[l]; A1 = cp[64 + l]; A2 = cp[128 + l]; A3 = cp[192 + l];
    }

#pragma unroll 1
    for (int r = 0; r < NR; ++r) {
        // ---- early B-row loads (f32 original layout, wave-coalesced);
        //      issued before the poll so IC latency hides under the spin ----
        float Bf[16];
        {
            const float* bp = mat32 + (size_t)xs[2 * r + 1] * TN_D * TN_D +
                              (size_t)(UPB * b) * TN_D + tid;
#pragma unroll
            for (int m = 0; m < 16; ++m) Bf[m] = bp[(size_t)m * TN_D];
        }

        // ---- acquire v_{2r}: sum 64 tagged partials (pipelined 8x8) ----
        if (r == 0) {
            lv[tid] = left[tid];
        } else {
            const u64* ap = acc + (size_t)((r - 1) & 1) * NBLK * TN_D + tid;
            const uint32_t want = (uint32_t)r;
            float sum = 0.f;
            u64 buf[8], nxt[8];
#pragma unroll
            for (int k = 0; k < 8; ++k) buf[k] = aload(ap + (size_t)k * TN_D);
#pragma unroll 1
            for (int g = 0; g < 8; ++g) {
                if (g < 7) {
#pragma unroll
                    for (int k = 0; k < 8; ++k)
                        nxt[k] = aload(ap + (size_t)((g + 1) * 8 + k) * TN_D);
                }
#pragma unroll
                for (int k = 0; k < 8; ++k) {
                    u64 u = buf[k];
                    const u64* p = ap + (size_t)(g * 8 + k) * TN_D;
                    while ((uint32_t)(u >> 32) != want) u = aload(p);
                    sum += __uint_as_float((uint32_t)u);
                }
#pragma unroll
                for (int k = 0; k < 8; ++k) buf[k] = nxt[k];
            }
            lv[tid] = sum;
        }
        __syncthreads();

        // ---- phase A: u[iw] = v . coreT[s0][iw][:]  (conflict-free b128) ----
        const float4* vv = (const float4*)lv;
        float ua = dot4h(vv[l], A0) + dot4h(vv[64 + l], A1) +
                   dot4h(vv[128 + l], A2) + dot4h(vv[192 + l], A3);
#pragma unroll
        for (int off = 32; off; off >>= 1) ua += __shfl_down(ua, off, 64);
        if (l == 0) wl[w] = ua;
        {   // prefetch next round's A column (consumed after next barrier pair)
            const int s2 = (2 * r + 2 < TN_F) ? xs[2 * r + 2] : 0;
            const half4_t* cp = (const half4_t*)(matT + ((size_t)s2 * TN_D + iw) * TN_D);
            nA0 = cp[l]; nA1 = cp[64 + l]; nA2 = cp[128 + l]; nA3 = cp[192 + l];
        }
        __syncthreads();

        // ---- phase B: partial[tid] = sum_m u[16b+m] * B[16b+m][tid] ----
        const float4* w4 = (const float4*)wl;  // LDS broadcast, conflict-free
        const float4 W0 = w4[0], W1 = w4[1], W2 = w4[2], W3 = w4[3];
        float p = W0.x * Bf[0]  + W0.y * Bf[1]  + W0.z * Bf[2]  + W0.w * Bf[3]
                + W1.x * Bf[4]  + W1.y * Bf[5]  + W1.z * Bf[6]  + W1.w * Bf[7]
                + W2.x * Bf[8]  + W2.y * Bf[9]  + W2.z * Bf[10] + W2.w * Bf[11]
                + W3.x * Bf[12] + W3.y * Bf[13] + W3.z * Bf[14] + W3.w * Bf[15];
        const u64 pack = ((u64)(uint32_t)(r + 1) << 32) | (u64)__float_as_uint(p);
        __hip_atomic_store(acc + (size_t)(r & 1) * NBLK * TN_D + (size_t)b * TN_D + tid,
                           pack, __ATOMIC_RELAXED, __HIP_MEMORY_SCOPE_AGENT);

        A0 = nA0; A1 = nA1; A2 = nA2; A3 = nA3;
    }

    // ---- final: v_F = sum of round NR-1 partials; dot right. block 0 only ----
    if (b == 0) {
        const u64* ap = acc + (size_t)((NR - 1) & 1) * NBLK * TN_D + tid;
        const uint32_t want = (uint32_t)NR;
        float sum = 0.f;
#pragma unroll 1
        for (int g = 0; g < NBLK; ++g) {
            const u64* p = ap + (size_t)g * TN_D;
            u64 u = aload(p);
            while ((uint32_t)(u >> 32) != want) u = aload(p);
            sum += __uint_as_float((uint32_t)u);
        }
        float pr = sum * right[tid];
#pragma unroll
        for (int off = 32; off; off >>= 1) pr += __shfl_down(pr, off, 64);
        __syncthreads();
        if (l == 0) wl[w] = pr;
        __syncthreads();
        if (tid == 0) {
            float s = 0.f;
#pragma unroll
            for (int k = 0; k < UPB; ++k) s += wl[k];
            out[0] = s;
        }
    }
}

// ---------------------------------------------------------------------------
// Fallback (tiny workspace): R2-structure fp32, no transpose.
// ---------------------------------------------------------------------------
__device__ __forceinline__ float4 poll4(const uint32_t* vp) {
    const unsigned long long* p = (const unsigned long long*)vp;
    unsigned long long a = __hip_atomic_load(p, __ATOMIC_RELAXED, __HIP_MEMORY_SCOPE_AGENT);
    unsigned long long b = __hip_atomic_load(p + 1, __ATOMIC_RELAXED, __HIP_MEMORY_SCOPE_AGENT);
    while ((uint32_t)a == SENT32 || (uint32_t)(a >> 32) == SENT32)
        a = __hip_atomic_load(p, __ATOMIC_RELAXED, __HIP_MEMORY_SCOPE_AGENT);
    while ((uint32_t)b == SENT32 || (uint32_t)(b >> 32) == SENT32)
        b = __hip_atomic_load(p + 1, __ATOMIC_RELAXED, __HIP_MEMORY_SCOPE_AGENT);
    return make_float4(__uint_as_float((uint32_t)a), __uint_as_float((uint32_t)(a >> 32)),
                       __uint_as_float((uint32_t)b), __uint_as_float((uint32_t)(b >> 32)));
}

__global__ __launch_bounds__(256, 1) void tn_chain_f32(const int* __restrict__ x,
                                                       const float* __restrict__ mat,
                                                       const float* __restrict__ left,
                                                       const float* __restrict__ right,
                                                       float* __restrict__ vg,
                                                       float* __restrict__ out) {
    __shared__ float4 lv[2][TN_D / 4];
    __shared__ float red[4];
    const int tid = threadIdx.x;
    const int w = tid >> 6;
    const int l = tid & 63;
    const int j = blockIdx.x * 4 + w;

    for (int t = 0; t < TN_F; ++t) {
        if (t == 0) lv[0][tid] = ((const float4*)left)[tid];
        else lv[t & 1][tid] = poll4((const uint32_t*)vg + (size_t)(t - 1) * TN_D + 4 * tid);
        __syncthreads();
        const float* mp = mat + (size_t)x[t] * TN_D * TN_D + j;
        const float4* vv = lv[t & 1];
        float acc = 0.f;
#pragma unroll
        for (int k = 0; k < 4; ++k) {
            const int i = 4 * l + 256 * k;
            const float4 v = vv[l + 64 * k];
            acc += v.x * mp[(size_t)i * TN_D] + v.y * mp[(size_t)(i + 1) * TN_D] +
                   v.z * mp[(size_t)(i + 2) * TN_D] + v.w * mp[(size_t)(i + 3) * TN_D];
        }
#pragma unroll
        for (int off = 32; off; off >>= 1) acc += __shfl_down(acc, off, 64);
        if (l == 0)
            __hip_atomic_store((uint32_t*)vg + (size_t)t * TN_D + j, __float_as_uint(acc),
                               __ATOMIC_RELAXED, __HIP_MEMORY_SCOPE_AGENT);
    }
    if (blockIdx.x == 0) {
        float4 v = poll4((const uint32_t*)vg + (size_t)(TN_F - 1) * TN_D + 4 * tid);
        const float4 r4 = ((const float4*)right)[tid];
        float p = v.x * r4.x + v.y * r4.y + v.z * r4.z + v.w * r4.w;
#pragma unroll
        for (int off = 32; off; off >>= 1) p += __shfl_down(p, off, 64);
        if (l == 0) red[w] = p;
        __syncthreads();
        if (tid == 0) out[0] = red[0] + red[1] + red[2] + red[3];
    }
}

extern "C" void kernel_launch(void* const* d_in, const int* in_sizes, int n_in,
                              void* d_out, int out_size, void* d_ws, size_t ws_size,
                              hipStream_t stream) {
    const int* x = (const int*)d_in[0];
    const float* core = (const float*)d_in[1];
    const float* left = (const float*)d_in[2];
    const float* right = (const float*)d_in[3];
    float* out = (float*)d_out;

    const int nsym = in_sizes[1] / (TN_D * TN_D);
    const size_t coreTBytes = (size_t)in_sizes[1] * sizeof(_Float16);   // 64 MB
    const size_t accBytes = (size_t)2 * NBLK * TN_D * sizeof(u64);      // 1 MB

    if (ws_size >= coreTBytes + accBytes) {
        _Float16* coreT = (_Float16*)d_ws;
        u64* acc = (u64*)((char*)d_ws + coreTBytes);
        hipMemsetAsync(acc, 0, accBytes, stream);   // tag 0 != any wanted tag >= 1
        tn_transpose<<<dim3(16, 16, nsym), dim3(16, 16), 0, stream>>>(core, coreT);
        tn_chain_fused<<<NBLK, 1024, 0, stream>>>(x, coreT, core, left, right, acc, out);
    } else {
        float* vg = (float*)d_ws;
        const size_t vbufBytes = (size_t)TN_F * TN_D * sizeof(float);
        hipMemsetAsync(vg, 0xAA, vbufBytes, stream);
        tn_chain_f32<<<256, 256, 0, stream>>>(x, core, left, right, vg, out);
    }
}

// Round 5
// 1861.176 us; speedup vs baseline: 3.0484x; 3.0484x over previous
//
#include <hip/hip_runtime.h>
#include <stdint.h>

#define TN_D 1024
#define TN_F 1024
#define SENT32 0xAAAAAAAAu
#define NBLK 64
#define CPB 16  // columns per block (1 per wave, 16 waves)

typedef _Float16 half4_t __attribute__((ext_vector_type(4)));

// ---------------------------------------------------------------------------
// Transpose + convert: core[s][i][j] f32 -> coreT[s][j][i] f16.
// ---------------------------------------------------------------------------
__global__ __launch_bounds__(256) void tn_transpose(const float* __restrict__ core,
                                                    _Float16* __restrict__ coreT) {
    __shared__ float tile[64][65];
    const int s = blockIdx.z;
    const size_t base = (size_t)s * TN_D * TN_D;
    const int j0 = blockIdx.x * 64;
    const int i0 = blockIdx.y * 64;
    const int tx = threadIdx.x;
    const int ty = threadIdx.y;
#pragma unroll
    for (int r = 0; r < 4; ++r) {
        const int ii = ty + 16 * r;
        const float4 v = *(const float4*)&core[base + (size_t)(i0 + ii) * TN_D + j0 + 4 * tx];
        tile[ii][4 * tx + 0] = v.x; tile[ii][4 * tx + 1] = v.y;
        tile[ii][4 * tx + 2] = v.z; tile[ii][4 * tx + 3] = v.w;
    }
    __syncthreads();
#pragma unroll
    for (int r = 0; r < 4; ++r) {
        const int jj = ty + 16 * r;
        _Float16 h4[4];
        h4[0] = (_Float16)tile[4 * tx + 0][jj];
        h4[1] = (_Float16)tile[4 * tx + 1][jj];
        h4[2] = (_Float16)tile[4 * tx + 2][jj];
        h4[3] = (_Float16)tile[4 * tx + 3][jj];
        *(uint64_t*)&coreT[base + (size_t)(j0 + jj) * TN_D + i0 + 4 * tx] = *(uint64_t*)h4;
    }
}

__device__ __forceinline__ uint32_t aload(const uint32_t* p) {
    return __hip_atomic_load(p, __ATOMIC_RELAXED, __HIP_MEMORY_SCOPE_AGENT);
}

// Poll seeded with a speculative early load (issued during the previous
// step's compute phase); spins only if the seed still shows the sentinel.
__device__ __forceinline__ float pollv(const uint32_t* p, uint32_t seed) {
    uint32_t u = seed;
    while (u == SENT32) u = aload(p);
    return __uint_as_float(u);
}

__device__ __forceinline__ float dot4h(float4 a, half4_t h) {
    return a.x * (float)h[0] + a.y * (float)h[1] + a.z * (float)h[2] + a.w * (float)h[3];
}

// ---------------------------------------------------------------------------
// Persistent chain, f16 matrix. 64 blocks x 1024 threads (16 waves); wave w
// owns column j = 16*blk + w. Per step:
//   poll:    thread tid polls ONE dword of the previous v-row (seeded by a
//            speculative load issued last step), writes it to LDS; barrier.
//   dot:     wave w dots its register-prefetched f16 column vs LDS v using
//            the conflict-free b128 pattern (lane l owns elements
//            {4l, 256+4l, 512+4l, 768+4l}; R3-measured 0 bank conflicts).
//   gather:  lane0 writes the wave dot to plain LDS; ONE barrier; wave0's
//            16 lanes issue a single coalesced 64B agent store per block
//            (R3 proved scattered dword stores cost +1.9 us/step).
// lv is single-buffered: the gather barrier orders all dot-reads of lv
// before any next-step overwrite. redv reuse is ordered by the v-ready
// barrier of the next step.
// ---------------------------------------------------------------------------
__global__ __launch_bounds__(1024, 1) void tn_chain_f16(const int* __restrict__ x,
                                                        const _Float16* __restrict__ mat,
                                                        const float* __restrict__ left,
                                                        const float* __restrict__ right,
                                                        float* __restrict__ vg,
                                                        float* __restrict__ out) {
    __shared__ __align__(16) float lv[TN_D];  // broadcast v
    __shared__ float redv[CPB];               // per-wave dot results (plain)
    __shared__ int xs[TN_F];                  // symbol stream
    __shared__ float red2[CPB];

    const int tid = threadIdx.x;
    const int w = tid >> 6;
    const int l = tid & 63;
    const int j = blockIdx.x * CPB + w;

    xs[tid] = x[tid];
    __syncthreads();

    half4_t A0, A1, A2, A3, B0, B1, B2, B3;
    {
        const half4_t* cp = (const half4_t*)(mat + ((size_t)xs[0] * TN_D + j) * TN_D);
        A0 = cp[l]; A1 = cp[64 + l]; A2 = cp[128 + l]; A3 = cp[192 + l];
    }

    uint32_t spec = SENT32;  // speculative poll seed for the next consumed row

    for (int t = 0; t < TN_F; t += 2) {
        const int s1 = xs[t + 1];
        const int s2 = xs[(t + 2 < TN_F) ? t + 2 : TN_F - 1];

        // ================= even step t (registers A) =================
        if (t == 0) lv[tid] = left[tid];
        else        lv[tid] = pollv((const uint32_t*)vg + (size_t)(t - 1) * TN_D + tid, spec);
        __syncthreads();  // v ready
        {   // prefetch col for t+1 (drained at first use, a step away)
            const half4_t* cp = (const half4_t*)(mat + ((size_t)s1 * TN_D + j) * TN_D);
            B0 = cp[l]; B1 = cp[64 + l]; B2 = cp[128 + l]; B3 = cp[192 + l];
        }
        {
            const float4* vv = (const float4*)lv;
            float acc = dot4h(vv[l], A0) + dot4h(vv[64 + l], A1) +
                        dot4h(vv[128 + l], A2) + dot4h(vv[192 + l], A3);
#pragma unroll
            for (int off = 32; off; off >>= 1) acc += __shfl_down(acc, off, 64);
            if (l == 0) redv[w] = acc;
            // speculative load of the row being produced now (consumed next)
            spec = aload((const uint32_t*)vg + (size_t)t * TN_D + tid);
            __syncthreads();  // gather barrier: redv complete, lv reads done
            if (w == 0 && l < CPB)
                __hip_atomic_store((uint32_t*)vg + (size_t)t * TN_D + blockIdx.x * CPB + l,
                                   __float_as_uint(redv[l]),
                                   __ATOMIC_RELAXED, __HIP_MEMORY_SCOPE_AGENT);
        }

        // ================= odd step t+1 (registers B) =================
        lv[tid] = pollv((const uint32_t*)vg + (size_t)t * TN_D + tid, spec);
        __syncthreads();  // v ready
        {   // prefetch col for t+2
            const half4_t* cp = (const half4_t*)(mat + ((size_t)s2 * TN_D + j) * TN_D);
            A0 = cp[l]; A1 = cp[64 + l]; A2 = cp[128 + l]; A3 = cp[192 + l];
        }
        {
            const float4* vv = (const float4*)lv;
            float acc = dot4h(vv[l], B0) + dot4h(vv[64 + l], B1) +
                        dot4h(vv[128 + l], B2) + dot4h(vv[192 + l], B3);
#pragma unroll
            for (int off = 32; off; off >>= 1) acc += __shfl_down(acc, off, 64);
            if (l == 0) redv[w] = acc;
            spec = aload((const uint32_t*)vg + (size_t)(t + 1) * TN_D + tid);
            __syncthreads();  // gather barrier
            if (w == 0 && l < CPB)
                __hip_atomic_store((uint32_t*)vg + (size_t)(t + 1) * TN_D + blockIdx.x * CPB + l,
                                   __float_as_uint(redv[l]),
                                   __ATOMIC_RELAXED, __HIP_MEMORY_SCOPE_AGENT);
        }
    }

    // ---- final dot with right boundary: block 0 ----
    if (blockIdx.x == 0) {
        float v = pollv((const uint32_t*)vg + (size_t)(TN_F - 1) * TN_D + tid, spec);
        float p = v * right[tid];
#pragma unroll
        for (int off = 32; off; off >>= 1) p += __shfl_down(p, off, 64);
        if (l == 0) red2[w] = p;
        __syncthreads();
        if (tid == 0) {
            float s = 0.f;
#pragma unroll
            for (int k = 0; k < CPB; ++k) s += red2[k];
            out[0] = s;
        }
    }
}

// ---------------------------------------------------------------------------
// Fallback (tiny workspace): R2-structure fp32, no transpose.
// ---------------------------------------------------------------------------
__device__ __forceinline__ float4 poll4(const uint32_t* vp) {
    const unsigned long long* p = (const unsigned long long*)vp;
    unsigned long long a = __hip_atomic_load(p, __ATOMIC_RELAXED, __HIP_MEMORY_SCOPE_AGENT);
    unsigned long long b = __hip_atomic_load(p + 1, __ATOMIC_RELAXED, __HIP_MEMORY_SCOPE_AGENT);
    while ((uint32_t)a == SENT32 || (uint32_t)(a >> 32) == SENT32)
        a = __hip_atomic_load(p, __ATOMIC_RELAXED, __HIP_MEMORY_SCOPE_AGENT);
    while ((uint32_t)b == SENT32 || (uint32_t)(b >> 32) == SENT32)
        b = __hip_atomic_load(p + 1, __ATOMIC_RELAXED, __HIP_MEMORY_SCOPE_AGENT);
    return make_float4(__uint_as_float((uint32_t)a), __uint_as_float((uint32_t)(a >> 32)),
                       __uint_as_float((uint32_t)b), __uint_as_float((uint32_t)(b >> 32)));
}

__global__ __launch_bounds__(256, 1) void tn_chain_f32(const int* __restrict__ x,
                                                       const float* __restrict__ mat,
                                                       const float* __restrict__ left,
                                                       const float* __restrict__ right,
                                                       float* __restrict__ vg,
                                                       float* __restrict__ out) {
    __shared__ float4 lv[2][TN_D / 4];
    __shared__ float red[4];
    const int tid = threadIdx.x;
    const int w = tid >> 6;
    const int l = tid & 63;
    const int j = blockIdx.x * 4 + w;

    for (int t = 0; t < TN_F; ++t) {
        if (t == 0) lv[0][tid] = ((const float4*)left)[tid];
        else lv[t & 1][tid] = poll4((const uint32_t*)vg + (size_t)(t - 1) * TN_D + 4 * tid);
        __syncthreads();
        const float* mp = mat + (size_t)x[t] * TN_D * TN_D + j;
        const float4* vv = lv[t & 1];
        float acc = 0.f;
#pragma unroll
        for (int k = 0; k < 4; ++k) {
            const int i = 4 * l + 256 * k;
            const float4 v = vv[l + 64 * k];
            acc += v.x * mp[(size_t)i * TN_D] + v.y * mp[(size_t)(i + 1) * TN_D] +
                   v.z * mp[(size_t)(i + 2) * TN_D] + v.w * mp[(size_t)(i + 3) * TN_D];
        }
#pragma unroll
        for (int off = 32; off; off >>= 1) acc += __shfl_down(acc, off, 64);
        if (l == 0)
            __hip_atomic_store((uint32_t*)vg + (size_t)t * TN_D + j, __float_as_uint(acc),
                               __ATOMIC_RELAXED, __HIP_MEMORY_SCOPE_AGENT);
    }
    if (blockIdx.x == 0) {
        float4 v = poll4((const uint32_t*)vg + (size_t)(TN_F - 1) * TN_D + 4 * tid);
        const float4 r4 = ((const float4*)right)[tid];
        float p = v.x * r4.x + v.y * r4.y + v.z * r4.z + v.w * r4.w;
#pragma unroll
        for (int off = 32; off; off >>= 1) p += __shfl_down(p, off, 64);
        if (l == 0) red[w] = p;
        __syncthreads();
        if (tid == 0) out[0] = red[0] + red[1] + red[2] + red[3];
    }
}

extern "C" void kernel_launch(void* const* d_in, const int* in_sizes, int n_in,
                              void* d_out, int out_size, void* d_ws, size_t ws_size,
                              hipStream_t stream) {
    const int* x = (const int*)d_in[0];
    const float* core = (const float*)d_in[1];
    const float* left = (const float*)d_in[2];
    const float* right = (const float*)d_in[3];
    float* out = (float*)d_out;

    const int nsym = in_sizes[1] / (TN_D * TN_D);
    const size_t coreTBytes = (size_t)in_sizes[1] * sizeof(_Float16);  // 64 MB
    const size_t vbufBytes = (size_t)TN_F * TN_D * sizeof(float);      // 4 MB

    if (ws_size >= coreTBytes + vbufBytes) {
        _Float16* coreT = (_Float16*)d_ws;
        float* vg = (float*)((char*)d_ws + coreTBytes);
        hipMemsetAsync(vg, 0xAA, vbufBytes, stream);
        tn_transpose<<<dim3(16, 16, nsym), dim3(16, 16), 0, stream>>>(core, coreT);
        tn_chain_f16<<<NBLK, 1024, 0, stream>>>(x, coreT, left, right, vg, out);
    } else {
        float* vg = (float*)d_ws;
        hipMemsetAsync(vg, 0xAA, vbufBytes, stream);
        tn_chain_f32<<<256, 256, 0, stream>>>(x, core, left, right, vg, out);
    }
}